// Round 3
// baseline (392.846 us; speedup 1.0000x reference)
//
#include <hip/hip_runtime.h>
#include <hip/hip_bf16.h>

// B=8, N=2048, DIN=256, DOUT=256
// Ne = H@W ; M1 = G@Ne ; M2 = G^T@Ne
// out[:,0:256]   = relu(0.5*(M1+M2))
// out[:,256:512] = relu(G^T @ (M1 * inv_rs))
// out[:,512:768] = relu(G   @ (M2 * inv_cs))
//
// R11: Gbf/GbfT stored TILED: [tr][tc][128][128] bf16 (32 KB contiguous tiles).
// R2 evidence: two structurally different cvt_g versions both stuck at 2.47 TB/s
// (occupancy 17% vs 33%, LDS vs register transpose) -> pattern-limited, not
// structure-limited. Row-major writes were 256 B chunks @ 4 KB stride = one DRAM
// page per chunk. Tiled layout makes each block's Gbf/GbfT writes one 32 KB
// sequential region, and mgemm A-staging reads 32 KB-local instead of
// 128 B @ 4 KB stride.

constexpr int NN = 2048;
constexpr long GSTR = (long)NN * NN;

using frag8   = __attribute__((ext_vector_type(8))) short;   // 8 bf16
using floatx4 = __attribute__((ext_vector_type(4))) float;
using ush8    = __attribute__((ext_vector_type(8))) unsigned short;

__device__ inline unsigned short f2bf(float x) {
    unsigned u = __float_as_uint(x);
    u += 0x7FFF + ((u >> 16) & 1);   // RNE
    return (unsigned short)(u >> 16);
}
__device__ inline float bf2f(unsigned short h) {
    return __uint_as_float((unsigned)h << 16);
}
__device__ inline ushort2 pk2(float a, float b) {
    union { __hip_bfloat162 h; ushort2 u; } cv;
    cv.h = __float22bfloat162_rn(float2{a, b});
    return cv.u;
}
__device__ inline void gload_lds16(const void* g, void* l) {
    __builtin_amdgcn_global_load_lds(
        (const __attribute__((address_space(1))) void*)g,
        (__attribute__((address_space(3))) void*)l, 16, 0, 0);
}

enum { EPI_NE = 0, EPI_M1 = 1, EPI_P2 = 2, EPI_O3 = 3 };
enum { A_F32ROW = 0, A_DMA = 1 };

// C[i,j] = sum_k Alog[i,k] * Bt[j,k]; Bt bf16 [n][K] staged via global_load_lds.
// A_DMA: A is TILED [r>>7][k>>7][128][128] (tile = 16384 shorts); requires TM=128.
// LDS (As/Bs): row stride 64 shorts; 16B chunk c of row r at slot c^(r&7)
//   -> fragment ds_read_b128 2-way (free), staging fully coalesced.
// Tile TM x 64, BK=64, 4 waves in 2x2 (wave = TM/2 rows x 32 cols).
// 1D grid, XCD-aware decode: xcd = bx&7 owns i-tiles {xcd, xcd+8, ...}; within an
// XCD the NJ j-tiles sharing an A-tile are temporally adjacent -> A-tile hits L2.
template <int EPI, int AMODE, int TM, int NJ>
__global__ __launch_bounds__(256) void mgemm(
    const void* __restrict__ Aptr,
    const unsigned short* __restrict__ B0,
    const unsigned short* __restrict__ B1,     // P2: M1sT (j0>=256 B-source + out1 reconstruct)
    const float* __restrict__ rsraw,           // P2: raw row sums (un-scale M1sT)
    unsigned short* __restrict__ CsT,          // transposed bf16 out [256][2048]
    float* __restrict__ outp,                  // fp32 out base (stride 768)
    const float* __restrict__ scale,           // M1: inv_rs ; P2: inv_cs
    int K, int lda, long strideA, long sB)
{
    constexpr int MF = TM / 32;                // m-frags per wave
    __shared__ __align__(16) unsigned short As[TM * 64];
    __shared__ __align__(16) unsigned short Bs[64 * 64];

    const int t  = threadIdx.x;
    const int bx = blockIdx.x;
    const int xcd = bx & 7;
    const int kk  = bx >> 3;
    constexpr int PER = NJ * 8;                // (j,b) combos per i-tile-group
    const int itile = xcd + 8 * (kk / PER);    // PER is pow2 -> shift
    const int rem   = kk & (PER - 1);
    const int bb    = rem / NJ;                // NJ pow2 -> shift
    const int jt    = rem & (NJ - 1);
    const int i0b = itile * TM;                // batch-local row tile
    const int j0  = jt * 64;

    const unsigned short* Btb =
        ((EPI == EPI_P2 && j0 >= 256) ? B1 + (long)(j0 - 256) * K
                                      : B0 + (long)j0 * K) + (long)bb * sB;

    const int w = t >> 6, l = t & 63;
    const int wm = w >> 1, wn = w & 1;
    const int quad = l >> 4, c15 = l & 15;

    const int lr  = l >> 3, ls = l & 7;  // DMA: row-in-8, slot

    floatx4 acc[MF][2] = {};

    for (int k0 = 0; k0 < K; k0 += 64) {
        // ---- stage A
        if constexpr (AMODE == A_DMA) {
            // tiled A: base of tile (itile, k0>>7) + in-tile (row)*128 + (k0&127)
            const unsigned short* Au = (const unsigned short*)Aptr
                + (long)bb * strideA
                + (((long)itile * (K >> 7) + (k0 >> 7)) << 14);
            const int kin = k0 & 127;
            #pragma unroll
            for (int q = 0; q < TM / 32; ++q) {
                const int rt = q * 32 + w * 8;
                gload_lds16(Au + (rt + lr) * 128 + kin + ((ls ^ lr) << 3),
                            &As[rt * 64]);
            }
        } else {  // A_F32ROW (NE over fp32 H), TM=64: 16 floats/thread
            const float* Af = (const float*)Aptr + (long)bb * strideA;
            const int ar  = t >> 2;
            const int ac0 = (t & 3) * 2;
            const float* ap = Af + (long)(i0b + ar) * lda + k0 + ac0 * 8;
            const float4 x0 = *(const float4*)(ap + 0);
            const float4 x1 = *(const float4*)(ap + 4);
            const float4 x2 = *(const float4*)(ap + 8);
            const float4 x3 = *(const float4*)(ap + 12);
            union { ush8 v; ushort2 u2[4]; } p0, p1;
            p0.u2[0] = pk2(x0.x, x0.y); p0.u2[1] = pk2(x0.z, x0.w);
            p0.u2[2] = pk2(x1.x, x1.y); p0.u2[3] = pk2(x1.z, x1.w);
            p1.u2[0] = pk2(x2.x, x2.y); p1.u2[1] = pk2(x2.z, x2.w);
            p1.u2[2] = pk2(x3.x, x3.y); p1.u2[3] = pk2(x3.z, x3.w);
            const int sw = ar & 7;
            *(ush8*)&As[ar * 64 + ((ac0 ^ sw) << 3)]       = p0.v;
            *(ush8*)&As[ar * 64 + (((ac0 + 1) ^ sw) << 3)] = p1.v;
        }
        // ---- stage B (always DMA, row-major [n][K])
        #pragma unroll
        for (int q = 0; q < 2; ++q) {
            const int rt = w * 16 + q * 8;
            gload_lds16(Btb + (long)(rt + lr) * K + k0 + ((ls ^ lr) << 3),
                        &Bs[rt * 64]);
        }
        __syncthreads();

        #pragma unroll
        for (int ks = 0; ks < 2; ++ks) {
            frag8 af[MF], bfv[2];
            const int swr = c15 & 7;
            #pragma unroll
            for (int mt = 0; mt < MF; ++mt)
                af[mt] = *(const frag8*)&As[(wm * (TM / 2) + mt * 16 + c15) * 64
                                            + (((ks * 4 + quad) ^ swr) << 3)];
            #pragma unroll
            for (int nt = 0; nt < 2; ++nt)
                bfv[nt] = *(const frag8*)&Bs[(wn * 32 + nt * 16 + c15) * 64
                                             + (((ks * 4 + quad) ^ swr) << 3)];
            #pragma unroll
            for (int mt = 0; mt < MF; ++mt)
                #pragma unroll
                for (int nt = 0; nt < 2; ++nt)
                    acc[mt][nt] = __builtin_amdgcn_mfma_f32_16x16x32_bf16(
                        af[mt], bfv[nt], acc[mt][nt], 0, 0, 0);
        }
        __syncthreads();
    }

    // ---- epilogue: C/D layout col=lane&15, row=quad*4+reg
    const long rowb = (long)bb * NN;
    #pragma unroll
    for (int mt = 0; mt < MF; ++mt) {
        const int il = wm * (TM / 2) + mt * 16 + quad * 4;
        const int ib = i0b + il;
        float4 s4 = make_float4(1.f, 1.f, 1.f, 1.f);
        if constexpr (EPI == EPI_M1) s4 = *(const float4*)(scale + rowb + ib);
        if constexpr (EPI == EPI_P2) {
            if (j0 < 256) s4 = *(const float4*)(scale + rowb + ib);
        }
        #pragma unroll
        for (int nt = 0; nt < 2; ++nt) {
            floatx4 v = acc[mt][nt];
            const int gj = j0 + wn * 32 + nt * 16 + c15;
            if constexpr (EPI == EPI_NE) {
                union { ushort4 v; ushort2 u2[2]; } p;
                p.u2[0] = pk2(v[0], v[1]); p.u2[1] = pk2(v[2], v[3]);
                *(ushort4*)(CsT + ((long)bb * 256 + gj) * 2048 + ib) = p.v;
            } else if constexpr (EPI == EPI_M1) {
                union { ushort4 v; ushort2 u2[2]; } p;
                p.u2[0] = pk2(v[0] * s4.x, v[1] * s4.y);
                p.u2[1] = pk2(v[2] * s4.z, v[3] * s4.w);
                *(ushort4*)(CsT + ((long)bb * 256 + gj) * 2048 + ib) = p.v;
            } else if constexpr (EPI == EPI_P2) {
                if (j0 < 256) {
                    union { ushort4 v; ushort2 u2[2]; } p;
                    p.u2[0] = pk2(v[0] * s4.x, v[1] * s4.y);
                    p.u2[1] = pk2(v[2] * s4.z, v[3] * s4.w);
                    *(ushort4*)(CsT + ((long)bb * 256 + gj) * 2048 + ib) = p.v;
                    // out1: reconstruct M1 = M1sT * rs_raw
                    const float4 rr = *(const float4*)(rsraw + rowb + ib);
                    const ushort4 m1p = *(const ushort4*)(B1 + ((long)bb * 256 + gj) * 2048 + ib);
                    const float m1v[4] = {bf2f(m1p.x) * rr.x, bf2f(m1p.y) * rr.y,
                                          bf2f(m1p.z) * rr.z, bf2f(m1p.w) * rr.w};
                    #pragma unroll
                    for (int r = 0; r < 4; ++r)
                        outp[(rowb + ib + r) * 768 + gj] = fmaxf(0.5f * (v[r] + m1v[r]), 0.f);
                } else {
                    #pragma unroll
                    for (int r = 0; r < 4; ++r)
                        outp[(rowb + ib + r) * 768 + gj] = fmaxf(v[r], 0.f);  // gj in [256,512)
                }
            } else {  // EPI_O3
                #pragma unroll
                for (int r = 0; r < 4; ++r)
                    outp[(rowb + ib + r) * 768 + 512 + gj] = fmaxf(v[r], 0.f);
            }
        }
    }
}

// ---- fused: G fp32 -> Gbf + GbfT (both TILED) + row/col partial sums ----
// Thread owns an 8x8 block (wave = 64x64 sub-tile, 2x2 waves per 128x128 tile):
//   - all 16 float4 loads issued, sched_barrier(0) pins them ahead
//   - 8x8 bf16 transpose in registers (16-bit interleave, 2 bit-ops/dword)
//   - Gbf tile (by,bx) and GbfT tile (bx,by) each written as one 32 KB
//     contiguous region per block -> sequential HBM write streams
//   - row/col sums: shfl_xor trees, 32 partials per batch, no LDS, no barrier
__global__ __launch_bounds__(256) void cvt_g(
    const float* __restrict__ G,
    unsigned short* __restrict__ Gbf, unsigned short* __restrict__ GbfT,
    float* __restrict__ prs, float* __restrict__ pcs)
{
    const int b  = blockIdx.z;
    const int j0 = blockIdx.x * 128, i0 = blockIdx.y * 128;
    const int t  = threadIdx.x;
    const int w  = t >> 6, l = t & 63;
    const int wm = w >> 1, wn = w & 1;     // i-half, j-half of the 128x128 tile
    const int rg = l >> 3, c = l & 7;      // i-block, j-block within 64x64

    const int ib = i0 + wm * 64 + rg * 8;  // global row base (8 rows)
    const int jb = j0 + wn * 64 + c * 8;   // global col base (8 cols)
    const int il = wm * 64 + rg * 8;       // in-tile row base
    const int jl = wn * 64 + c * 8;        // in-tile col base

    // tiled bases: Gbf tile (i>>7=by, j>>7=bx), GbfT tile (j>>7=bx, i>>7=by)
    const long gbase = (long)b * GSTR + (((long)blockIdx.y * 16 + blockIdx.x) << 14);
    const long tbase = (long)b * GSTR + (((long)blockIdx.x * 16 + blockIdx.y) << 14);

    const float* gp = G + (long)b * GSTR + (long)ib * NN + jb;

    // ---- issue all 16 loads; forbid sinking them into the compute
    float4 xs[16];
    #pragma unroll
    for (int r = 0; r < 8; ++r) {
        xs[2 * r]     = *(const float4*)(gp + (long)r * NN);
        xs[2 * r + 1] = *(const float4*)(gp + (long)r * NN + 4);
    }
    __builtin_amdgcn_sched_barrier(0);

    union RowU { ush8 v; ushort2 u2[4]; unsigned u4[4]; };
    RowU rows[8];
    float csum[8] = {};
    float rsum[8];

    #pragma unroll
    for (int r = 0; r < 8; ++r) {
        const float4 x0 = xs[2 * r], x1 = xs[2 * r + 1];
        RowU rw;
        rw.u2[0] = pk2(x0.x, x0.y); rw.u2[1] = pk2(x0.z, x0.w);
        rw.u2[2] = pk2(x1.x, x1.y); rw.u2[3] = pk2(x1.z, x1.w);
        rows[r] = rw;
        *(ush8*)(Gbf + gbase + (long)(il + r) * 128 + jl) = rw.v;
        rsum[r] = x0.x + x0.y + x0.z + x0.w + x1.x + x1.y + x1.z + x1.w;
        csum[0] += x0.x; csum[1] += x0.y; csum[2] += x0.z; csum[3] += x0.w;
        csum[4] += x1.x; csum[5] += x1.y; csum[6] += x1.z; csum[7] += x1.w;
    }

    // ---- row sums: reduce across c (lane bits 0..2) -> 64-col partial
    #pragma unroll
    for (int r = 0; r < 8; ++r) {
        rsum[r] += __shfl_xor(rsum[r], 1);
        rsum[r] += __shfl_xor(rsum[r], 2);
        rsum[r] += __shfl_xor(rsum[r], 4);
    }
    if (c == 0) {
        float* pp = prs + ((long)b * 32 + blockIdx.x * 2 + wn) * NN + ib;
        *(float4*)pp       = make_float4(rsum[0], rsum[1], rsum[2], rsum[3]);
        *(float4*)(pp + 4) = make_float4(rsum[4], rsum[5], rsum[6], rsum[7]);
    }

    // ---- col sums: reduce across rg (lane bits 3..5) -> 64-row partial
    #pragma unroll
    for (int e = 0; e < 8; ++e) {
        csum[e] += __shfl_xor(csum[e], 8);
        csum[e] += __shfl_xor(csum[e], 16);
        csum[e] += __shfl_xor(csum[e], 32);
    }
    if (rg == 0) {
        float* pp = pcs + ((long)b * 32 + blockIdx.y * 2 + wm) * NN + jb;
        *(float4*)pp       = make_float4(csum[0], csum[1], csum[2], csum[3]);
        *(float4*)(pp + 4) = make_float4(csum[4], csum[5], csum[6], csum[7]);
    }

    // ---- 8x8 bf16 transpose in registers: 16-bit interleave of row pairs.
    // cols[j].u4[p] = {rows[2p] elem j (lo), rows[2p+1] elem j (hi)}
    RowU cols[8];
    #pragma unroll
    for (int p = 0; p < 4; ++p) {
        #pragma unroll
        for (int k = 0; k < 4; ++k) {
            const unsigned a = rows[2 * p].u4[k], bq = rows[2 * p + 1].u4[k];
            cols[2 * k].u4[p]     = (a & 0xffffu) | (bq << 16);
            cols[2 * k + 1].u4[p] = (a >> 16) | (bq & 0xffff0000u);
        }
    }
    #pragma unroll
    for (int j = 0; j < 8; ++j)
        *(ush8*)(GbfT + tbase + (long)(jl + j) * 128 + il) = cols[j].v;
}

// reduce partials + W transpose: y=0 -> inv_rs+rs_raw ; y=1 -> inv_cs ; y=2 -> Wt
__global__ __launch_bounds__(256) void finalize(
    const float* __restrict__ prs, const float* __restrict__ pcs,
    float* __restrict__ inv_rs, float* __restrict__ rs_raw,
    float* __restrict__ inv_cs,
    const float* __restrict__ W, unsigned short* __restrict__ Wt)
{
    const int idx = blockIdx.x * 256 + threadIdx.x;   // 0..16383
    if (blockIdx.y == 0) {
        const int b = idx >> 11, i = idx & 2047;
        float s = 0.f;
        #pragma unroll
        for (int jc = 0; jc < 32; ++jc) s += prs[((long)b * 32 + jc) * NN + i];
        inv_rs[idx] = 1.0f / s;
        rs_raw[idx] = s;
    } else if (blockIdx.y == 1) {
        const int b = idx >> 11, i = idx & 2047;
        float s = 0.f;
        #pragma unroll
        for (int ic = 0; ic < 32; ++ic) s += pcs[((long)b * 32 + ic) * NN + i];
        inv_cs[idx] = 1.0f / s;
    } else {
        #pragma unroll
        for (int e = 0; e < 4; ++e) {
            const int flat = idx * 4 + e;              // 0..65535
            const int j = flat >> 8, k = flat & 255;
            Wt[flat] = f2bf(W[(long)k * 256 + j]);
        }
    }
}

extern "C" void kernel_launch(void* const* d_in, const int* in_sizes, int n_in,
                              void* d_out, int out_size, void* d_ws, size_t ws_size,
                              hipStream_t stream)
{
    constexpr int B = 8;
    const float* H = (const float*)d_in[0];
    const float* G = (const float*)d_in[1];
    const float* W = (const float*)d_in[2];
    float* out = (float*)d_out;

    unsigned short* ws16 = (unsigned short*)d_ws;
    unsigned short* Gbf  = ws16;                          // 33,554,432 shorts (tiled)
    unsigned short* GbfT = Gbf  + (long)B * GSTR;         // 33,554,432 (tiled)
    unsigned short* Wt   = GbfT + (long)B * GSTR;         // 65,536
    unsigned short* NeT  = Wt   + 65536;                  // 4,194,304
    unsigned short* M1sT = NeT  + 4194304;                // 4,194,304
    unsigned short* M2sT = M1sT + 4194304;                // 4,194,304
    float* inv_rs = (float*)(M2sT + 4194304);             // 16384
    float* rs_raw = inv_rs + 16384;
    float* inv_cs = rs_raw + 16384;
    float* prs    = inv_cs + 16384;                       // 8*32*2048
    float* pcs    = prs + (long)B * 32 * NN;              // 8*32*2048
    // total ~166 MB (ws = 512 MiB per harness fill WRITE_SIZE)

    cvt_g<<<dim3(16, 16, 8), 256, 0, stream>>>(G, Gbf, GbfT, prs, pcs);
    finalize<<<dim3(64, 3), 256, 0, stream>>>(prs, pcs, inv_rs, rs_raw, inv_cs, W, Wt);

    const long sNT = 256L * NN;
    // NeT = (H@W)^T : A=H fp32 [b][2048][256]  (TM=64, 32 i-tiles x 4 j x 8 b)
    mgemm<EPI_NE, A_F32ROW, 64, 4><<<1024, 256, 0, stream>>>(
        H, Wt, nullptr, nullptr, NeT, nullptr, nullptr,
        256, 256, 2048L * 256, 0);
    // M1sT = (G@Ne * inv_rs)^T   (TM=128: 16 i-tiles x 4 j x 8 b; A=Gbf tiled)
    mgemm<EPI_M1, A_DMA, 128, 4><<<512, 256, 0, stream>>>(
        Gbf, NeT, nullptr, nullptr, M1sT, nullptr, inv_rs,
        2048, 2048, GSTR, sNT);
    // P2: A=GbfT tiled, B=[NeT ; M1sT] -> M2sT(scaled inv_cs) + out1 + out2 (8 j-tiles)
    mgemm<EPI_P2, A_DMA, 128, 8><<<1024, 256, 0, stream>>>(
        GbfT, NeT, M1sT, rs_raw, M2sT, out, inv_cs,
        2048, 2048, GSTR, sNT);
    // out3 = relu(G @ M2s)  (A=Gbf tiled)
    mgemm<EPI_O3, A_DMA, 128, 4><<<512, 256, 0, stream>>>(
        Gbf, M2sT, nullptr, nullptr, nullptr, out, nullptr,
        2048, 2048, GSTR, sNT);
}

// Round 4
// 374.914 us; speedup vs baseline: 1.0478x; 1.0478x over previous
//
#include <hip/hip_runtime.h>
#include <hip/hip_bf16.h>

// B=8, N=2048, DIN=256, DOUT=256
// Ne = H@W ; M1 = G@Ne ; M2 = G^T@Ne
// out[:,0:256]   = relu(0.5*(M1+M2))
// out[:,256:512] = relu(G^T @ (M1 * inv_rs))
// out[:,512:768] = relu(G   @ (M2 * inv_cs))
//
// R12: split cvt_g -> cvt_stream (sequential-read G->Gbf(tiled) + row sums +
// col partials) + cvt_t (tiled 128x128 bf16 transpose Gbf->GbfT, both sides
// sequential, source L3-hot). Diagnostic: 3 fused variants all plateaued at
// 2.6 TB/s; the split isolates read-stream vs transpose cost.
// P2 GEMM widened to 128-j tiles (32 MFMA per barrier pair instead of 16,
// still 2 blocks/CU).

constexpr int NN = 2048;
constexpr long GSTR = (long)NN * NN;

using frag8   = __attribute__((ext_vector_type(8))) short;   // 8 bf16
using floatx4 = __attribute__((ext_vector_type(4))) float;
using ush8    = __attribute__((ext_vector_type(8))) unsigned short;

__device__ inline unsigned short f2bf(float x) {
    unsigned u = __float_as_uint(x);
    u += 0x7FFF + ((u >> 16) & 1);   // RNE
    return (unsigned short)(u >> 16);
}
__device__ inline float bf2f(unsigned short h) {
    return __uint_as_float((unsigned)h << 16);
}
__device__ inline ushort2 pk2(float a, float b) {
    union { __hip_bfloat162 h; ushort2 u; } cv;
    cv.h = __float22bfloat162_rn(float2{a, b});
    return cv.u;
}
__device__ inline void gload_lds16(const void* g, void* l) {
    __builtin_amdgcn_global_load_lds(
        (const __attribute__((address_space(1))) void*)g,
        (__attribute__((address_space(3))) void*)l, 16, 0, 0);
}

enum { EPI_NE = 0, EPI_M1 = 1, EPI_P2 = 2, EPI_O3 = 3 };
enum { A_F32ROW = 0, A_DMA = 1 };

// C[i,j] = sum_k Alog[i,k] * Bt[j,k]; Bt bf16 [n][K] staged via global_load_lds.
// A_DMA: A is TILED [r>>7][k>>7][128][128] (tile = 16384 shorts); requires TM=128.
// LDS (As/Bs): row stride 64 shorts; 16B chunk c of row r at slot c^(r&7).
// Tile TM x WJ, BK=64, 4 waves in 2x2 (wave = TM/2 rows x WJ/2 cols).
// 1D grid, XCD-aware decode.
template <int EPI, int AMODE, int TM, int WJ, int NJ>
__global__ __launch_bounds__(256) void mgemm(
    const void* __restrict__ Aptr,
    const unsigned short* __restrict__ B0,
    const unsigned short* __restrict__ B1,     // P2: M1sT (j0>=256 B-source + out0 reconstruct)
    const float* __restrict__ rsraw,           // P2: raw row sums (un-scale M1sT)
    unsigned short* __restrict__ CsT,          // transposed bf16 out [256][2048]
    float* __restrict__ outp,                  // fp32 out base (stride 768)
    const float* __restrict__ scale,           // M1: inv_rs ; P2: inv_cs
    int K, int lda, long strideA, long sB)
{
    constexpr int MF = TM / 32;                // m-frags per wave
    constexpr int NF = WJ / 32;                // n-frags per wave
    __shared__ __align__(16) unsigned short As[TM * 64];
    __shared__ __align__(16) unsigned short Bs[WJ * 64];

    const int t  = threadIdx.x;
    const int bx = blockIdx.x;
    const int xcd = bx & 7;
    const int kk  = bx >> 3;
    constexpr int PER = NJ * 8;                // (j,b) combos per i-tile-group
    const int itile = xcd + 8 * (kk / PER);
    const int rem   = kk & (PER - 1);
    const int bb    = rem / NJ;
    const int jt    = rem & (NJ - 1);
    const int i0b = itile * TM;                // batch-local row tile
    const int j0  = jt * WJ;

    const unsigned short* Btb =
        ((EPI == EPI_P2 && j0 >= 256) ? B1 + (long)(j0 - 256) * K
                                      : B0 + (long)j0 * K) + (long)bb * sB;

    const int w = t >> 6, l = t & 63;
    const int wm = w >> 1, wn = w & 1;
    const int quad = l >> 4, c15 = l & 15;

    const int lr  = l >> 3, ls = l & 7;  // DMA: row-in-8, slot

    floatx4 acc[MF][NF] = {};

    for (int k0 = 0; k0 < K; k0 += 64) {
        // ---- stage A
        if constexpr (AMODE == A_DMA) {
            // tiled A: base of tile (itile, k0>>7) + in-tile (row)*128 + (k0&127)
            const unsigned short* Au = (const unsigned short*)Aptr
                + (long)bb * strideA
                + (((long)itile * (K >> 7) + (k0 >> 7)) << 14);
            const int kin = k0 & 127;
            #pragma unroll
            for (int q = 0; q < TM / 32; ++q) {
                const int rt = q * 32 + w * 8;
                gload_lds16(Au + (rt + lr) * 128 + kin + ((ls ^ lr) << 3),
                            &As[rt * 64]);
            }
        } else {  // A_F32ROW (NE over fp32 H), TM=64: 16 floats/thread
            const float* Af = (const float*)Aptr + (long)bb * strideA;
            const int ar  = t >> 2;
            const int ac0 = (t & 3) * 2;
            const float* ap = Af + (long)(i0b + ar) * lda + k0 + ac0 * 8;
            const float4 x0 = *(const float4*)(ap + 0);
            const float4 x1 = *(const float4*)(ap + 4);
            const float4 x2 = *(const float4*)(ap + 8);
            const float4 x3 = *(const float4*)(ap + 12);
            union { ush8 v; ushort2 u2[4]; } p0, p1;
            p0.u2[0] = pk2(x0.x, x0.y); p0.u2[1] = pk2(x0.z, x0.w);
            p0.u2[2] = pk2(x1.x, x1.y); p0.u2[3] = pk2(x1.z, x1.w);
            p1.u2[0] = pk2(x2.x, x2.y); p1.u2[1] = pk2(x2.z, x2.w);
            p1.u2[2] = pk2(x3.x, x3.y); p1.u2[3] = pk2(x3.z, x3.w);
            const int sw = ar & 7;
            *(ush8*)&As[ar * 64 + ((ac0 ^ sw) << 3)]       = p0.v;
            *(ush8*)&As[ar * 64 + (((ac0 + 1) ^ sw) << 3)] = p1.v;
        }
        // ---- stage B (always DMA, row-major [n][K])
        #pragma unroll
        for (int q = 0; q < WJ / 32; ++q) {
            const int rt = q * 32 + w * 8;
            gload_lds16(Btb + (long)(rt + lr) * K + k0 + ((ls ^ lr) << 3),
                        &Bs[rt * 64]);
        }
        __syncthreads();

        #pragma unroll
        for (int ks = 0; ks < 2; ++ks) {
            frag8 af[MF], bfv[NF];
            const int swr = c15 & 7;
            #pragma unroll
            for (int mt = 0; mt < MF; ++mt)
                af[mt] = *(const frag8*)&As[(wm * (TM / 2) + mt * 16 + c15) * 64
                                            + (((ks * 4 + quad) ^ swr) << 3)];
            #pragma unroll
            for (int nt = 0; nt < NF; ++nt)
                bfv[nt] = *(const frag8*)&Bs[(wn * (WJ / 2) + nt * 16 + c15) * 64
                                             + (((ks * 4 + quad) ^ swr) << 3)];
            #pragma unroll
            for (int mt = 0; mt < MF; ++mt)
                #pragma unroll
                for (int nt = 0; nt < NF; ++nt)
                    acc[mt][nt] = __builtin_amdgcn_mfma_f32_16x16x32_bf16(
                        af[mt], bfv[nt], acc[mt][nt], 0, 0, 0);
        }
        __syncthreads();
    }

    // ---- epilogue: C/D layout col=lane&15, row=quad*4+reg
    const long rowb = (long)bb * NN;
    #pragma unroll
    for (int mt = 0; mt < MF; ++mt) {
        const int il = wm * (TM / 2) + mt * 16 + quad * 4;
        const int ib = i0b + il;
        float4 s4 = make_float4(1.f, 1.f, 1.f, 1.f);
        if constexpr (EPI == EPI_M1) s4 = *(const float4*)(scale + rowb + ib);
        if constexpr (EPI == EPI_P2) {
            if (j0 < 256) s4 = *(const float4*)(scale + rowb + ib);
        }
        #pragma unroll
        for (int nt = 0; nt < NF; ++nt) {
            floatx4 v = acc[mt][nt];
            const int gj = j0 + wn * (WJ / 2) + nt * 16 + c15;
            if constexpr (EPI == EPI_NE) {
                union { ushort4 v; ushort2 u2[2]; } p;
                p.u2[0] = pk2(v[0], v[1]); p.u2[1] = pk2(v[2], v[3]);
                *(ushort4*)(CsT + ((long)bb * 256 + gj) * 2048 + ib) = p.v;
            } else if constexpr (EPI == EPI_M1) {
                union { ushort4 v; ushort2 u2[2]; } p;
                p.u2[0] = pk2(v[0] * s4.x, v[1] * s4.y);
                p.u2[1] = pk2(v[2] * s4.z, v[3] * s4.w);
                *(ushort4*)(CsT + ((long)bb * 256 + gj) * 2048 + ib) = p.v;
            } else if constexpr (EPI == EPI_P2) {
                if (j0 < 256) {
                    union { ushort4 v; ushort2 u2[2]; } p;
                    p.u2[0] = pk2(v[0] * s4.x, v[1] * s4.y);
                    p.u2[1] = pk2(v[2] * s4.z, v[3] * s4.w);
                    *(ushort4*)(CsT + ((long)bb * 256 + gj) * 2048 + ib) = p.v;
                    // out0: reconstruct M1 = M1sT * rs_raw
                    const float4 rr = *(const float4*)(rsraw + rowb + ib);
                    const ushort4 m1p = *(const ushort4*)(B1 + ((long)bb * 256 + gj) * 2048 + ib);
                    const float m1v[4] = {bf2f(m1p.x) * rr.x, bf2f(m1p.y) * rr.y,
                                          bf2f(m1p.z) * rr.z, bf2f(m1p.w) * rr.w};
                    #pragma unroll
                    for (int r = 0; r < 4; ++r)
                        outp[(rowb + ib + r) * 768 + gj] = fmaxf(0.5f * (v[r] + m1v[r]), 0.f);
                } else {
                    #pragma unroll
                    for (int r = 0; r < 4; ++r)
                        outp[(rowb + ib + r) * 768 + gj] = fmaxf(v[r], 0.f);  // gj in [256,512)
                }
            } else {  // EPI_O3
                #pragma unroll
                for (int r = 0; r < 4; ++r)
                    outp[(rowb + ib + r) * 768 + 512 + gj] = fmaxf(v[r], 0.f);
            }
        }
    }
}

// ---- cvt_stream: G fp32 -> Gbf (tiled) + FULL row sums + col partials ----
// Block = 16-row strip x full 2048 cols. Reads are 100% sequential (128 KB
// per block). Thread t owns cols t*8..t*8+7 across all 16 rows.
__global__ __launch_bounds__(256) void cvt_stream(
    const float* __restrict__ G,
    unsigned short* __restrict__ Gbf,          // tiled [16][16][128][128]
    float* __restrict__ pcs,                   // [b][128][2048] col partials
    float* __restrict__ inv_rs, float* __restrict__ rs_raw)
{
    __shared__ float sm[4][16];
    const int b  = blockIdx.y;
    const int s  = blockIdx.x;                 // strip 0..127
    const int i0 = s * 16;
    const int t  = threadIdx.x;
    const int c8 = t * 8;
    const int w  = t >> 6, l = t & 63;

    const float* gp = G + (long)b * GSTR + (long)i0 * NN + c8;
    unsigned short* gb = Gbf + (long)b * GSTR;
    const int tc = c8 >> 7, cin = c8 & 127;

    float csum[8] = {};
    float rp[16];

    #pragma unroll
    for (int r = 0; r < 16; ++r) {
        const float4 x0 = *(const float4*)(gp + (long)r * NN);
        const float4 x1 = *(const float4*)(gp + (long)r * NN + 4);
        union { ush8 v; ushort2 u2[4]; } pk;
        pk.u2[0] = pk2(x0.x, x0.y); pk.u2[1] = pk2(x0.z, x0.w);
        pk.u2[2] = pk2(x1.x, x1.y); pk.u2[3] = pk2(x1.z, x1.w);
        const int gi = i0 + r;
        *(ush8*)(gb + (((long)(gi >> 7) * 16 + tc) << 14) + ((gi & 127) << 7) + cin) = pk.v;
        rp[r] = x0.x + x0.y + x0.z + x0.w + x1.x + x1.y + x1.z + x1.w;
        csum[0] += x0.x; csum[1] += x0.y; csum[2] += x0.z; csum[3] += x0.w;
        csum[4] += x1.x; csum[5] += x1.y; csum[6] += x1.z; csum[7] += x1.w;
    }

    // col partials: each thread owns distinct cols -> direct store
    float* pp = pcs + ((long)b * 128 + s) * NN + c8;
    *(float4*)pp       = make_float4(csum[0], csum[1], csum[2], csum[3]);
    *(float4*)(pp + 4) = make_float4(csum[4], csum[5], csum[6], csum[7]);

    // row sums: wave shfl tree then cross-wave LDS combine
    #pragma unroll
    for (int r = 0; r < 16; ++r) {
        rp[r] += __shfl_xor(rp[r], 1);
        rp[r] += __shfl_xor(rp[r], 2);
        rp[r] += __shfl_xor(rp[r], 4);
        rp[r] += __shfl_xor(rp[r], 8);
        rp[r] += __shfl_xor(rp[r], 16);
        rp[r] += __shfl_xor(rp[r], 32);
    }
    if (l == 0) {
        #pragma unroll
        for (int r = 0; r < 16; ++r) sm[w][r] = rp[r];
    }
    __syncthreads();
    if (t < 16) {
        const float s_ = sm[0][t] + sm[1][t] + sm[2][t] + sm[3][t];
        rs_raw[(long)b * NN + i0 + t] = s_;
        inv_rs[(long)b * NN + i0 + t] = 1.0f / s_;
    }
}

// ---- cvt_t: tiled->tiled bf16 transpose. Block = one 128x128 tile.
// Reads and writes both 32 KB-sequential; source likely L3-hot after cvt_stream.
__global__ __launch_bounds__(256) void cvt_t(
    const unsigned short* __restrict__ Gbf, unsigned short* __restrict__ GbfT)
{
    const int b  = blockIdx.z;
    const int tr = blockIdx.y, tc = blockIdx.x;
    const long src = (long)b * GSTR + (((long)tr * 16 + tc) << 14);
    const long dst = (long)b * GSTR + (((long)tc * 16 + tr) << 14);
    const int t = threadIdx.x;
    const int w = t >> 6, l = t & 63;
    const int wm = w >> 1, wn = w & 1;
    const int rg = l >> 3, c = l & 7;
    const int il = wm * 64 + rg * 8;   // in-tile row base
    const int jl = wn * 64 + c * 8;    // in-tile col base

    union RowU { ush8 v; unsigned u4[4]; };
    RowU rows[8], cols[8];
    #pragma unroll
    for (int r = 0; r < 8; ++r)
        rows[r].v = *(const ush8*)(Gbf + src + (long)(il + r) * 128 + jl);
    __builtin_amdgcn_sched_barrier(0);

    // 8x8 bf16 transpose via 16-bit interleave (verified R2/R3)
    #pragma unroll
    for (int p = 0; p < 4; ++p) {
        #pragma unroll
        for (int k = 0; k < 4; ++k) {
            const unsigned a = rows[2 * p].u4[k], bq = rows[2 * p + 1].u4[k];
            cols[2 * k].u4[p]     = (a & 0xffffu) | (bq << 16);
            cols[2 * k + 1].u4[p] = (a >> 16) | (bq & 0xffff0000u);
        }
    }
    #pragma unroll
    for (int j = 0; j < 8; ++j)
        *(ush8*)(GbfT + dst + (long)(jl + j) * 128 + il) = cols[j].v;
}

// reduce col partials + W transpose: y=0 -> inv_cs ; y=1 -> Wt
__global__ __launch_bounds__(256) void finalize(
    const float* __restrict__ pcs,
    float* __restrict__ inv_cs,
    const float* __restrict__ W, unsigned short* __restrict__ Wt)
{
    const int idx = blockIdx.x * 256 + threadIdx.x;   // 0..16383
    if (blockIdx.y == 0) {
        const int b = idx >> 11, i = idx & 2047;
        float s = 0.f;
        for (int ic = 0; ic < 128; ++ic) s += pcs[((long)b * 128 + ic) * NN + i];
        inv_cs[idx] = 1.0f / s;
    } else {
        #pragma unroll
        for (int e = 0; e < 4; ++e) {
            const int flat = idx * 4 + e;              // 0..65535
            const int j = flat >> 8, k = flat & 255;
            Wt[flat] = f2bf(W[(long)k * 256 + j]);
        }
    }
}

extern "C" void kernel_launch(void* const* d_in, const int* in_sizes, int n_in,
                              void* d_out, int out_size, void* d_ws, size_t ws_size,
                              hipStream_t stream)
{
    constexpr int B = 8;
    const float* H = (const float*)d_in[0];
    const float* G = (const float*)d_in[1];
    const float* W = (const float*)d_in[2];
    float* out = (float*)d_out;

    unsigned short* ws16 = (unsigned short*)d_ws;
    unsigned short* Gbf  = ws16;                          // 33,554,432 shorts (tiled)
    unsigned short* GbfT = Gbf  + (long)B * GSTR;         // 33,554,432 (tiled)
    unsigned short* Wt   = GbfT + (long)B * GSTR;         // 65,536
    unsigned short* NeT  = Wt   + 65536;                  // 4,194,304
    unsigned short* M1sT = NeT  + 4194304;                // 4,194,304
    unsigned short* M2sT = M1sT + 4194304;                // 4,194,304
    float* inv_rs = (float*)(M2sT + 4194304);             // 16384
    float* rs_raw = inv_rs + 16384;
    float* inv_cs = rs_raw + 16384;
    float* pcs    = inv_cs + 16384;                       // 8*128*2048 = 2M floats
    // total ~170 MB (ws = 512 MiB)

    cvt_stream<<<dim3(128, 8), 256, 0, stream>>>(G, Gbf, pcs, inv_rs, rs_raw);
    cvt_t<<<dim3(16, 16, 8), 256, 0, stream>>>(Gbf, GbfT);
    finalize<<<dim3(64, 2), 256, 0, stream>>>(pcs, inv_cs, W, Wt);

    const long sNT = 256L * NN;
    // NeT = (H@W)^T : A=H fp32 [b][2048][256]  (TM=64, WJ=64, 32 i x 4 j x 8 b)
    mgemm<EPI_NE, A_F32ROW, 64, 64, 4><<<1024, 256, 0, stream>>>(
        H, Wt, nullptr, nullptr, NeT, nullptr, nullptr,
        256, 256, 2048L * 256, 0);
    // M1sT = (G@Ne * inv_rs)^T   (TM=128, WJ=64: 16 i x 4 j x 8 b; A=Gbf tiled)
    mgemm<EPI_M1, A_DMA, 128, 64, 4><<<512, 256, 0, stream>>>(
        Gbf, NeT, nullptr, nullptr, M1sT, nullptr, inv_rs,
        2048, 2048, GSTR, sNT);
    // P2: A=GbfT tiled, B=[NeT ; M1sT], WJ=128 (32 MFMA/K-step): 16 i x 4 j x 8 b
    mgemm<EPI_P2, A_DMA, 128, 128, 4><<<512, 256, 0, stream>>>(
        GbfT, NeT, M1sT, rs_raw, M2sT, out, inv_cs,
        2048, 2048, GSTR, sNT);
    // out2 = relu(G @ M2s)  (A=Gbf tiled, WJ=64)
    mgemm<EPI_O3, A_DMA, 128, 64, 4><<<512, 256, 0, stream>>>(
        Gbf, M2sT, nullptr, nullptr, nullptr, out, nullptr,
        2048, 2048, GSTR, sNT);
}

// Round 5
// 373.661 us; speedup vs baseline: 1.0513x; 1.0034x over previous
//
#include <hip/hip_runtime.h>
#include <hip/hip_bf16.h>

// B=8, N=2048, DIN=256, DOUT=256
// Ne = H@W ; M1 = G@Ne ; M2 = G^T@Ne
// out[:,0:256]   = relu(0.5*(M1+M2))
// out[:,256:512] = relu(G^T @ (M1 * inv_rs))
// out[:,512:768] = relu(G   @ (M2 * inv_cs))
//
// R13: pipelined mgemm (T3 minimum-2-phase). R4 accounting: three big GEMMs
// ~74us EACH (M1 17.2GF = 232 TF; P2 34.4GF = 465 TF, same duration despite
// 2x FLOP) -> duration set by K-steps x (staging + 2x syncthreads drain),
// MFMA free. New loop: LDS double-buffer, STAGE(next) issued BEFORE
// ds_read+MFMA(cur), single vmcnt(0)+s_barrier at step end (loads were in
// flight during the whole MFMA phase -> drain cheap). One barrier per K-step
// instead of two full-drain barriers. All GEMMs unified to A_DMA via
// pre-converted tiled Hbf (cvt_h).

constexpr int NN = 2048;
constexpr long GSTR = (long)NN * NN;

using frag8   = __attribute__((ext_vector_type(8))) short;   // 8 bf16
using floatx4 = __attribute__((ext_vector_type(4))) float;
using ush8    = __attribute__((ext_vector_type(8))) unsigned short;

__device__ inline unsigned short f2bf(float x) {
    unsigned u = __float_as_uint(x);
    u += 0x7FFF + ((u >> 16) & 1);   // RNE
    return (unsigned short)(u >> 16);
}
__device__ inline float bf2f(unsigned short h) {
    return __uint_as_float((unsigned)h << 16);
}
__device__ inline ushort2 pk2(float a, float b) {
    union { __hip_bfloat162 h; ushort2 u; } cv;
    cv.h = __float22bfloat162_rn(float2{a, b});
    return cv.u;
}
__device__ inline void gload_lds16(const void* g, void* l) {
    __builtin_amdgcn_global_load_lds(
        (const __attribute__((address_space(1))) void*)g,
        (__attribute__((address_space(3))) void*)l, 16, 0, 0);
}

enum { EPI_NE = 0, EPI_M1 = 1, EPI_P2 = 2, EPI_O3 = 3 };

// C[i,j] = sum_k A[i,k] * Bt[j,k].
// A is TILED bf16 [r>>7][k>>7][128][128] (tile = 16384 shorts); TM=128.
// Bt is row-major bf16 [n][K].
// LDS (As/Bs): row stride 64 shorts; 16B chunk c of row r at slot c^(r&7)
// (swizzle applied via pre-swizzled GLOBAL source addr; LDS dest linear).
// Tile TM x WJ, BK=64, 4 waves in 2x2 (wave = TM/2 rows x WJ/2 cols).
// Pipelined K-loop: dbuf LDS, stage(next) || compute(cur), ONE barrier/step.
template <int EPI, int TM, int WJ, int NJ>
__global__ __launch_bounds__(256) void mgemm(
    const unsigned short* __restrict__ Aptr,
    const unsigned short* __restrict__ B0,
    const unsigned short* __restrict__ B1,     // P2: M1sT (j0>=256 B-source + out0 reconstruct)
    const float* __restrict__ rsraw,           // P2: raw row sums (un-scale M1sT)
    unsigned short* __restrict__ CsT,          // transposed bf16 out [256][2048]
    float* __restrict__ outp,                  // fp32 out base (stride 768)
    const float* __restrict__ scale,           // M1: inv_rs ; P2: inv_cs
    int K, long strideA, long sB)
{
    constexpr int MF = TM / 32;                // m-frags per wave
    constexpr int NF = WJ / 32;                // n-frags per wave
    __shared__ __align__(16) unsigned short As[2][TM * 64];
    __shared__ __align__(16) unsigned short Bs[2][WJ * 64];

    const int t  = threadIdx.x;
    const int bx = blockIdx.x;
    const int xcd = bx & 7;
    const int kk  = bx >> 3;
    constexpr int PER = NJ * 8;                // (j,b) combos per i-tile-group
    const int itile = xcd + 8 * (kk / PER);
    const int rem   = kk & (PER - 1);
    const int bb    = rem / NJ;
    const int jt    = rem & (NJ - 1);
    const int i0b = itile * TM;                // batch-local row tile
    const int j0  = jt * WJ;

    const unsigned short* Btb =
        ((EPI == EPI_P2 && j0 >= 256) ? B1 + (long)(j0 - 256) * K
                                      : B0 + (long)j0 * K) + (long)bb * sB;
    const unsigned short* Ab = Aptr + (long)bb * strideA;

    const int w = t >> 6, l = t & 63;
    const int wm = w >> 1, wn = w & 1;
    const int quad = l >> 4, c15 = l & 15;

    const int lr  = l >> 3, ls = l & 7;  // DMA: row-in-8, slot

    floatx4 acc[MF][NF] = {};

    const int NT = K >> 6;

    auto stage = [&](int buf, int k0) {
        const unsigned short* Au = Ab + (((long)itile * (K >> 7) + (k0 >> 7)) << 14);
        const int kin = k0 & 127;
        #pragma unroll
        for (int q = 0; q < TM / 32; ++q) {
            const int rt = q * 32 + w * 8;
            gload_lds16(Au + (rt + lr) * 128 + kin + ((ls ^ lr) << 3),
                        &As[buf][rt * 64]);
        }
        #pragma unroll
        for (int q = 0; q < WJ / 32; ++q) {
            const int rt = q * 32 + w * 8;
            gload_lds16(Btb + (long)(rt + lr) * K + k0 + ((ls ^ lr) << 3),
                        &Bs[buf][rt * 64]);
        }
    };

    // ---- prologue: stage tile 0, wait, barrier
    stage(0, 0);
    asm volatile("s_waitcnt vmcnt(0)" ::: "memory");
    __builtin_amdgcn_s_barrier();
    __builtin_amdgcn_sched_barrier(0);

    int cur = 0;
    for (int tt = 0; tt < NT; ++tt) {
        if (tt + 1 < NT) stage(cur ^ 1, (tt + 1) << 6);   // issue next-tile loads
        __builtin_amdgcn_sched_barrier(0);

        // ---- compute current buffer (compiler inserts lgkmcnt for ds_read->MFMA)
        #pragma unroll
        for (int ks = 0; ks < 2; ++ks) {
            frag8 af[MF], bfv[NF];
            const int swr = c15 & 7;
            #pragma unroll
            for (int mt = 0; mt < MF; ++mt)
                af[mt] = *(const frag8*)&As[cur][(wm * (TM / 2) + mt * 16 + c15) * 64
                                               + (((ks * 4 + quad) ^ swr) << 3)];
            #pragma unroll
            for (int nt = 0; nt < NF; ++nt)
                bfv[nt] = *(const frag8*)&Bs[cur][(wn * (WJ / 2) + nt * 16 + c15) * 64
                                                + (((ks * 4 + quad) ^ swr) << 3)];
            #pragma unroll
            for (int mt = 0; mt < MF; ++mt)
                #pragma unroll
                for (int nt = 0; nt < NF; ++nt)
                    acc[mt][nt] = __builtin_amdgcn_mfma_f32_16x16x32_bf16(
                        af[mt], bfv[nt], acc[mt][nt], 0, 0, 0);
        }

        if (tt + 1 < NT) {
            // next tile's loads had the whole MFMA phase in flight -> cheap drain
            asm volatile("s_waitcnt vmcnt(0)" ::: "memory");
            __builtin_amdgcn_s_barrier();
            __builtin_amdgcn_sched_barrier(0);
        }
        cur ^= 1;
    }

    // ---- epilogue: C/D layout col=lane&15, row=quad*4+reg
    const long rowb = (long)bb * NN;
    #pragma unroll
    for (int mt = 0; mt < MF; ++mt) {
        const int il = wm * (TM / 2) + mt * 16 + quad * 4;
        const int ib = i0b + il;
        float4 s4 = make_float4(1.f, 1.f, 1.f, 1.f);
        if constexpr (EPI == EPI_M1) s4 = *(const float4*)(scale + rowb + ib);
        if constexpr (EPI == EPI_P2) {
            if (j0 < 256) s4 = *(const float4*)(scale + rowb + ib);
        }
        #pragma unroll
        for (int nt = 0; nt < NF; ++nt) {
            floatx4 v = acc[mt][nt];
            const int gj = j0 + wn * (WJ / 2) + nt * 16 + c15;
            if constexpr (EPI == EPI_NE) {
                union { ushort4 v; ushort2 u2[2]; } p;
                p.u2[0] = pk2(v[0], v[1]); p.u2[1] = pk2(v[2], v[3]);
                *(ushort4*)(CsT + ((long)bb * 256 + gj) * 2048 + ib) = p.v;
            } else if constexpr (EPI == EPI_M1) {
                union { ushort4 v; ushort2 u2[2]; } p;
                p.u2[0] = pk2(v[0] * s4.x, v[1] * s4.y);
                p.u2[1] = pk2(v[2] * s4.z, v[3] * s4.w);
                *(ushort4*)(CsT + ((long)bb * 256 + gj) * 2048 + ib) = p.v;
            } else if constexpr (EPI == EPI_P2) {
                if (j0 < 256) {
                    union { ushort4 v; ushort2 u2[2]; } p;
                    p.u2[0] = pk2(v[0] * s4.x, v[1] * s4.y);
                    p.u2[1] = pk2(v[2] * s4.z, v[3] * s4.w);
                    *(ushort4*)(CsT + ((long)bb * 256 + gj) * 2048 + ib) = p.v;
                    // out0: reconstruct M1 = M1sT * rs_raw
                    const float4 rr = *(const float4*)(rsraw + rowb + ib);
                    const ushort4 m1p = *(const ushort4*)(B1 + ((long)bb * 256 + gj) * 2048 + ib);
                    const float m1v[4] = {bf2f(m1p.x) * rr.x, bf2f(m1p.y) * rr.y,
                                          bf2f(m1p.z) * rr.z, bf2f(m1p.w) * rr.w};
                    #pragma unroll
                    for (int r = 0; r < 4; ++r)
                        outp[(rowb + ib + r) * 768 + gj] = fmaxf(0.5f * (v[r] + m1v[r]), 0.f);
                } else {
                    #pragma unroll
                    for (int r = 0; r < 4; ++r)
                        outp[(rowb + ib + r) * 768 + gj] = fmaxf(v[r], 0.f);  // gj in [256,512)
                }
            } else {  // EPI_O3
                #pragma unroll
                for (int r = 0; r < 4; ++r)
                    outp[(rowb + ib + r) * 768 + 512 + gj] = fmaxf(v[r], 0.f);
            }
        }
    }
}

// ---- cvt_stream: G fp32 -> Gbf (tiled) + FULL row sums + col partials ----
// Block = 16-row strip x full 2048 cols. Reads are 100% sequential (128 KB
// per block). Thread t owns cols t*8..t*8+7 across all 16 rows.
__global__ __launch_bounds__(256) void cvt_stream(
    const float* __restrict__ G,
    unsigned short* __restrict__ Gbf,          // tiled [16][16][128][128]
    float* __restrict__ pcs,                   // [b][128][2048] col partials
    float* __restrict__ inv_rs, float* __restrict__ rs_raw)
{
    __shared__ float sm[4][16];
    const int b  = blockIdx.y;
    const int s  = blockIdx.x;                 // strip 0..127
    const int i0 = s * 16;
    const int t  = threadIdx.x;
    const int c8 = t * 8;
    const int w  = t >> 6, l = t & 63;

    const float* gp = G + (long)b * GSTR + (long)i0 * NN + c8;
    unsigned short* gb = Gbf + (long)b * GSTR;
    const int tc = c8 >> 7, cin = c8 & 127;

    float csum[8] = {};
    float rp[16];

    #pragma unroll
    for (int r = 0; r < 16; ++r) {
        const float4 x0 = *(const float4*)(gp + (long)r * NN);
        const float4 x1 = *(const float4*)(gp + (long)r * NN + 4);
        union { ush8 v; ushort2 u2[4]; } pk;
        pk.u2[0] = pk2(x0.x, x0.y); pk.u2[1] = pk2(x0.z, x0.w);
        pk.u2[2] = pk2(x1.x, x1.y); pk.u2[3] = pk2(x1.z, x1.w);
        const int gi = i0 + r;
        *(ush8*)(gb + (((long)(gi >> 7) * 16 + tc) << 14) + ((gi & 127) << 7) + cin) = pk.v;
        rp[r] = x0.x + x0.y + x0.z + x0.w + x1.x + x1.y + x1.z + x1.w;
        csum[0] += x0.x; csum[1] += x0.y; csum[2] += x0.z; csum[3] += x0.w;
        csum[4] += x1.x; csum[5] += x1.y; csum[6] += x1.z; csum[7] += x1.w;
    }

    // col partials: each thread owns distinct cols -> direct store
    float* pp = pcs + ((long)b * 128 + s) * NN + c8;
    *(float4*)pp       = make_float4(csum[0], csum[1], csum[2], csum[3]);
    *(float4*)(pp + 4) = make_float4(csum[4], csum[5], csum[6], csum[7]);

    // row sums: wave shfl tree then cross-wave LDS combine
    #pragma unroll
    for (int r = 0; r < 16; ++r) {
        rp[r] += __shfl_xor(rp[r], 1);
        rp[r] += __shfl_xor(rp[r], 2);
        rp[r] += __shfl_xor(rp[r], 4);
        rp[r] += __shfl_xor(rp[r], 8);
        rp[r] += __shfl_xor(rp[r], 16);
        rp[r] += __shfl_xor(rp[r], 32);
    }
    if (l == 0) {
        #pragma unroll
        for (int r = 0; r < 16; ++r) sm[w][r] = rp[r];
    }
    __syncthreads();
    if (t < 16) {
        const float s_ = sm[0][t] + sm[1][t] + sm[2][t] + sm[3][t];
        rs_raw[(long)b * NN + i0 + t] = s_;
        inv_rs[(long)b * NN + i0 + t] = 1.0f / s_;
    }
}

// ---- cvt_t: tiled->tiled bf16 transpose. Block = one 128x128 tile.
__global__ __launch_bounds__(256) void cvt_t(
    const unsigned short* __restrict__ Gbf, unsigned short* __restrict__ GbfT)
{
    const int b  = blockIdx.z;
    const int tr = blockIdx.y, tc = blockIdx.x;
    const long src = (long)b * GSTR + (((long)tr * 16 + tc) << 14);
    const long dst = (long)b * GSTR + (((long)tc * 16 + tr) << 14);
    const int t = threadIdx.x;
    const int w = t >> 6, l = t & 63;
    const int wm = w >> 1, wn = w & 1;
    const int rg = l >> 3, c = l & 7;
    const int il = wm * 64 + rg * 8;   // in-tile row base
    const int jl = wn * 64 + c * 8;    // in-tile col base

    union RowU { ush8 v; unsigned u4[4]; };
    RowU rows[8], cols[8];
    #pragma unroll
    for (int r = 0; r < 8; ++r)
        rows[r].v = *(const ush8*)(Gbf + src + (long)(il + r) * 128 + jl);
    __builtin_amdgcn_sched_barrier(0);

    // 8x8 bf16 transpose via 16-bit interleave (verified R2/R3)
    #pragma unroll
    for (int p = 0; p < 4; ++p) {
        #pragma unroll
        for (int k = 0; k < 4; ++k) {
            const unsigned a = rows[2 * p].u4[k], bq = rows[2 * p + 1].u4[k];
            cols[2 * k].u4[p]     = (a & 0xffffu) | (bq << 16);
            cols[2 * k + 1].u4[p] = (a >> 16) | (bq & 0xffff0000u);
        }
    }
    #pragma unroll
    for (int j = 0; j < 8; ++j)
        *(ush8*)(GbfT + dst + (long)(jl + j) * 128 + il) = cols[j].v;
}

// ---- cvt_h: H fp32 [b][2048][256] -> Hbf tiled [b][16][2][128][128] bf16 ----
__global__ __launch_bounds__(256) void cvt_h(
    const float* __restrict__ H, unsigned short* __restrict__ Hbf)
{
    const int b = blockIdx.y, it = blockIdx.x;
    const int t = threadIdx.x;
    const int rsub = t >> 5, c = (t & 31) * 8;
    const float* hp = H + ((long)b * 2048 + (long)it * 128) * 256;
    unsigned short* ob = Hbf + (long)b * (2048L * 256) + (((long)it * 2 + (c >> 7)) << 14);
    const int cin = c & 127;
    #pragma unroll
    for (int rr = 0; rr < 16; ++rr) {
        const int r = rr * 8 + rsub;
        const float4 x0 = *(const float4*)(hp + (long)r * 256 + c);
        const float4 x1 = *(const float4*)(hp + (long)r * 256 + c + 4);
        union { ush8 v; ushort2 u2[4]; } pk;
        pk.u2[0] = pk2(x0.x, x0.y); pk.u2[1] = pk2(x0.z, x0.w);
        pk.u2[2] = pk2(x1.x, x1.y); pk.u2[3] = pk2(x1.z, x1.w);
        *(ush8*)(ob + r * 128 + cin) = pk.v;
    }
}

// reduce col partials + W transpose: y=0 -> inv_cs ; y=1 -> Wt
__global__ __launch_bounds__(256) void finalize(
    const float* __restrict__ pcs,
    float* __restrict__ inv_cs,
    const float* __restrict__ W, unsigned short* __restrict__ Wt)
{
    const int idx = blockIdx.x * 256 + threadIdx.x;   // 0..16383
    if (blockIdx.y == 0) {
        const int b = idx >> 11, i = idx & 2047;
        float s = 0.f;
        for (int ic = 0; ic < 128; ++ic) s += pcs[((long)b * 128 + ic) * NN + i];
        inv_cs[idx] = 1.0f / s;
    } else {
        #pragma unroll
        for (int e = 0; e < 4; ++e) {
            const int flat = idx * 4 + e;              // 0..65535
            const int j = flat >> 8, k = flat & 255;
            Wt[flat] = f2bf(W[(long)k * 256 + j]);
        }
    }
}

extern "C" void kernel_launch(void* const* d_in, const int* in_sizes, int n_in,
                              void* d_out, int out_size, void* d_ws, size_t ws_size,
                              hipStream_t stream)
{
    constexpr int B = 8;
    const float* H = (const float*)d_in[0];
    const float* G = (const float*)d_in[1];
    const float* W = (const float*)d_in[2];
    float* out = (float*)d_out;

    unsigned short* ws16 = (unsigned short*)d_ws;
    unsigned short* Gbf  = ws16;                          // 33,554,432 shorts (tiled)
    unsigned short* GbfT = Gbf  + (long)B * GSTR;         // 33,554,432 (tiled)
    unsigned short* Wt   = GbfT + (long)B * GSTR;         // 65,536
    unsigned short* NeT  = Wt   + 65536;                  // 4,194,304
    unsigned short* M1sT = NeT  + 4194304;                // 4,194,304
    unsigned short* M2sT = M1sT + 4194304;                // 4,194,304
    unsigned short* Hbf  = M2sT + 4194304;                // 4,194,304 (tiled)
    float* inv_rs = (float*)(Hbf + 4194304);              // 16384
    float* rs_raw = inv_rs + 16384;
    float* inv_cs = rs_raw + 16384;
    float* pcs    = inv_cs + 16384;                       // 8*128*2048 = 2M floats
    // total ~178 MB (ws = 512 MiB)

    cvt_stream<<<dim3(128, 8), 256, 0, stream>>>(G, Gbf, pcs, inv_rs, rs_raw);
    cvt_t<<<dim3(16, 16, 8), 256, 0, stream>>>(Gbf, GbfT);
    cvt_h<<<dim3(16, 8), 256, 0, stream>>>(H, Hbf);
    finalize<<<dim3(64, 2), 256, 0, stream>>>(pcs, inv_cs, W, Wt);

    const long sNT = 256L * NN;
    // NeT = (H@W)^T : A=Hbf tiled (TM=128: 16 i x 4 j x 8 b), K=256
    mgemm<EPI_NE, 128, 64, 4><<<512, 256, 0, stream>>>(
        Hbf, Wt, nullptr, nullptr, NeT, nullptr, nullptr,
        256, 2048L * 256, 0);
    // M1sT = (G@Ne * inv_rs)^T   (A=Gbf tiled, 16 i x 4 j x 8 b)
    mgemm<EPI_M1, 128, 64, 4><<<512, 256, 0, stream>>>(
        Gbf, NeT, nullptr, nullptr, M1sT, nullptr, inv_rs,
        2048, GSTR, sNT);
    // P2: A=GbfT tiled, B=[NeT ; M1sT], WJ=128 (32 MFMA/K-step): 16 i x 4 j x 8 b
    mgemm<EPI_P2, 128, 128, 4><<<512, 256, 0, stream>>>(
        GbfT, NeT, M1sT, rs_raw, M2sT, out, inv_cs,
        2048, GSTR, sNT);
    // out2 = relu(G @ M2s)  (A=Gbf tiled)
    mgemm<EPI_O3, 128, 64, 4><<<512, 256, 0, stream>>>(
        Gbf, M2sT, nullptr, nullptr, nullptr, out, nullptr,
        2048, GSTR, sNT);
}

// Round 6
// 358.394 us; speedup vs baseline: 1.0961x; 1.0426x over previous
//
#include <hip/hip_runtime.h>
#include <hip/hip_bf16.h>

// B=8, N=2048, DIN=256, DOUT=256
// Ne = H@W ; M1 = G@Ne ; M2 = G^T@Ne
// out[:,0:256]   = relu(0.5*(M1+M2))
// out[:,256:512] = relu(G^T @ (M1 * inv_rs))
// out[:,512:768] = relu(G   @ (M2 * inv_cs))
//
// R14: FLIPPED skinny GEMMs. R5 evidence: old GEMMs ~74us each = ~5500 cyc/K-step
// (vs ~200 cyc MFMA) -> staging-traffic-bound; B-panels (8MB) re-read by blocks on
// all 8 XCDs (8x HBM duplication). Flip: compute C^T[256 dout][2048 n] with
// A = small matrix (NeT/M1sT/M2sT, 1-2MB/batch, L2-resident via bb->XCD mapping)
// and B = big G/G^T tiles streamed EXACTLY ONCE (each j-panel owned by 1 block).
//   GA: h=0: M1sT[d][a] = inv_rs[a] * sum_k NeT[d][k]*Gbf[a][k]
//       h=1: M2sT[d][a] = inv_cs[a] * sum_k NeT[d][k]*GbfT[a][k]
//   GB: h=0: out1^T[d][a] = sum_k M1sT[d][k]*GbfT[a][k] -> out[a][256+d]
//       h=1: out2^T[d][a] = sum_k M2sT[d][k]*Gbf[a][k]  -> out[a][512+d]
//   out0k: out[a][d] = relu(0.5*(M1sT[d][a]*rs_raw[a] + M2sT[d][a]*cs_raw[a]))
// TM=256 x WJ=64, 32 MFMA/wave/K-step, 512 blocks = 2/CU, LDS 2x80KB exact.

constexpr int NN = 2048;
constexpr long GSTR = (long)NN * NN;
constexpr long SDN = 256L * 2048;   // [dout][n] plane stride

using frag8   = __attribute__((ext_vector_type(8))) short;   // 8 bf16
using floatx4 = __attribute__((ext_vector_type(4))) float;
using ush8    = __attribute__((ext_vector_type(8))) unsigned short;

__device__ inline unsigned short f2bf(float x) {
    unsigned u = __float_as_uint(x);
    u += 0x7FFF + ((u >> 16) & 1);   // RNE
    return (unsigned short)(u >> 16);
}
__device__ inline float bf2f(unsigned short h) {
    return __uint_as_float((unsigned)h << 16);
}
__device__ inline ushort2 pk2(float a, float b) {
    union { __hip_bfloat162 h; ushort2 u; } cv;
    cv.h = __float22bfloat162_rn(float2{a, b});
    return cv.u;
}
__device__ inline void gload_lds16(const void* g, void* l) {
    __builtin_amdgcn_global_load_lds(
        (const __attribute__((address_space(1))) void*)g,
        (__attribute__((address_space(3))) void*)l, 16, 0, 0);
}

// ---- flipped GEMM: CT[d][a] = sum_k A[d][k] * Bt[a][k]
// A row-major [256][2048] (L2-resident small matrix), Bt TILED [a>>7][k>>7][128][128].
// 512 blocks: bb = bx&7 (-> XCD, pins A panel in that XCD's L2), jt = 0..31, h = 0/1.
// 4 waves 2x2: wave = 128 d-rows x 32 a-cols; acc[8][2]; BK=64, pipelined dbuf.
template <int PHASE>   // 0 = GA, 1 = GB
__global__ __launch_bounds__(256) void gemmF(
    const unsigned short* __restrict__ Aa,   // GA: NeT ; GB: M1sT
    const unsigned short* __restrict__ Ab,   // GB: M2sT
    const unsigned short* __restrict__ Gb,   // Gbf tiled
    const unsigned short* __restrict__ GbT,  // GbfT tiled
    unsigned short* __restrict__ C0,         // GA: M1sT
    unsigned short* __restrict__ C1,         // GA: M2sT
    float* __restrict__ outp,                // GB
    const float* __restrict__ s0,            // GA: inv_rs
    const float* __restrict__ s1)            // GA: inv_cs
{
    constexpr int TM = 256, NT = 32;         // K=2048, BK=64
    __shared__ __align__(16) unsigned short SH[2][(TM + 64) * 64];  // 2x40KB

    const int bx = blockIdx.x;
    const int bb = bx & 7;
    const int rr_ = bx >> 3;                 // 0..63
    const int jt = rr_ & 31;
    const int h  = rr_ >> 5;                 // 0/1
    const int j0 = jt * 64;

    const unsigned short* Ap =
        ((PHASE == 1 && h) ? Ab : Aa) + (long)bb * SDN;
    const unsigned short* Bp =
        (((PHASE == 0) == (h == 0)) ? Gb : GbT) + (long)bb * GSTR;

    const int t = threadIdx.x;
    const int w = t >> 6, l = t & 63;
    const int wm = w >> 1, wn = w & 1;
    const int quad = l >> 4, c15 = l & 15;
    const int lr = l >> 3, ls = l & 7;

    floatx4 acc[8][2] = {};

    auto stage = [&](int buf, int k0) {
        #pragma unroll
        for (int q = 0; q < 8; ++q) {        // A: 256 rows x 64 k
            const int rt = q * 32 + w * 8;
            gload_lds16(Ap + (long)(rt + lr) * 2048 + k0 + ((ls ^ lr) << 3),
                        &SH[buf][rt * 64]);
        }
        const unsigned short* Bt = Bp + (((long)(j0 >> 7) * 16 + (k0 >> 7)) << 14);
        const int rb = j0 & 127, kin = k0 & 127;
        #pragma unroll
        for (int q = 0; q < 2; ++q) {        // B: 64 rows x 64 k from one tile
            const int rt = q * 32 + w * 8;
            gload_lds16(Bt + (rb + rt + lr) * 128 + kin + ((ls ^ lr) << 3),
                        &SH[buf][TM * 64 + rt * 64]);
        }
    };

    stage(0, 0);
    asm volatile("s_waitcnt vmcnt(0)" ::: "memory");
    __builtin_amdgcn_s_barrier();
    __builtin_amdgcn_sched_barrier(0);

    int cur = 0;
    for (int tt = 0; tt < NT; ++tt) {
        if (tt + 1 < NT) stage(cur ^ 1, (tt + 1) << 6);
        __builtin_amdgcn_sched_barrier(0);
        #pragma unroll
        for (int ks = 0; ks < 2; ++ks) {
            frag8 af[8], bfv[2];
            const int swr = c15 & 7;
            #pragma unroll
            for (int mt = 0; mt < 8; ++mt)
                af[mt] = *(const frag8*)&SH[cur][(wm * 128 + mt * 16 + c15) * 64
                                                + (((ks * 4 + quad) ^ swr) << 3)];
            #pragma unroll
            for (int nt = 0; nt < 2; ++nt)
                bfv[nt] = *(const frag8*)&SH[cur][TM * 64 + (wn * 32 + nt * 16 + c15) * 64
                                                 + (((ks * 4 + quad) ^ swr) << 3)];
            #pragma unroll
            for (int mt = 0; mt < 8; ++mt)
                #pragma unroll
                for (int nt = 0; nt < 2; ++nt)
                    acc[mt][nt] = __builtin_amdgcn_mfma_f32_16x16x32_bf16(
                        af[mt], bfv[nt], acc[mt][nt], 0, 0, 0);
        }
        if (tt + 1 < NT) {
            asm volatile("s_waitcnt vmcnt(0)" ::: "memory");
            __builtin_amdgcn_s_barrier();
            __builtin_amdgcn_sched_barrier(0);
        }
        cur ^= 1;
    }

    __syncthreads();   // K-loop LDS reads done; reuse SH for transpose epilogue

    // C/D frag layout: col(a) = lane&15, row(d) = quad*4 + e
    if constexpr (PHASE == 0) {
        // scale by column a, bf16, LDS-transpose, store rows of [256][2048]
        unsigned short* T16 = &SH[0][0];     // [256][72] (72*2B = 16-aligned rows)
        #pragma unroll
        for (int nt = 0; nt < 2; ++nt) {
            const int jc = wn * 32 + nt * 16 + c15;
            const float sc = (h ? s1 : s0)[(long)bb * 2048 + j0 + jc];
            #pragma unroll
            for (int mt = 0; mt < 8; ++mt) {
                const floatx4 v = acc[mt][nt];
                const int ib = wm * 128 + mt * 16 + quad * 4;
                #pragma unroll
                for (int e = 0; e < 4; ++e)
                    T16[(ib + e) * 72 + jc] = f2bf(v[e] * sc);
            }
        }
        __syncthreads();
        unsigned short* Co = (h ? C1 : C0) + ((long)bb * 256 + t) * 2048 + j0;
        const unsigned short* Tr = T16 + t * 72;
        #pragma unroll
        for (int c2 = 0; c2 < 8; ++c2)
            *(ush8*)(Co + c2 * 8) = *(const ush8*)(Tr + c2 * 8);
    } else {
        // relu, fp32 LDS-transpose, store 64 out-rows x 256 contiguous floats
        float* TF = (float*)&SH[0][0];       // [64][260] (260*4B = 16-aligned rows)
        #pragma unroll
        for (int nt = 0; nt < 2; ++nt) {
            const int jc = wn * 32 + nt * 16 + c15;
            #pragma unroll
            for (int mt = 0; mt < 8; ++mt) {
                const floatx4 v = acc[mt][nt];
                const int ib = wm * 128 + mt * 16 + quad * 4;
                #pragma unroll
                for (int e = 0; e < 4; ++e)
                    TF[jc * 260 + ib + e] = fmaxf(v[e], 0.f);
            }
        }
        __syncthreads();
        const int jr = t >> 2, iq = t & 3;
        float* Op = outp + ((long)bb * 2048 + j0 + jr) * 768 + (h ? 512 : 256) + iq * 64;
        const float* Sp = TF + jr * 260 + iq * 64;
        #pragma unroll
        for (int c2 = 0; c2 < 16; ++c2)
            *(float4*)(Op + c2 * 4) = *(const float4*)(Sp + c2 * 4);
    }
}

// ---- out0k: out[a][0:256] = relu(0.5*(M1sT[d][a]*rs_raw[a] + M2sT[d][a]*cs_raw[a]))
// 8x8 register transpose (cvt_t pattern); block = 256 d x 64 a.
__global__ __launch_bounds__(256) void out0k(
    const unsigned short* __restrict__ M1sT, const unsigned short* __restrict__ M2sT,
    const float* __restrict__ rs_raw, const float* __restrict__ cs_raw,
    float* __restrict__ outp)
{
    const int bb = blockIdx.y, jt = blockIdx.x;   // jt: 0..31
    const int j0 = jt * 64;
    const int t = threadIdx.x;
    const int w = t >> 6, l = t & 63;
    const int rg = l >> 3, c = l & 7;
    const int ib = w * 64 + rg * 8;               // d base (8 rows)
    const int jb = j0 + c * 8;                    // a base (8 cols)
    const long ab = (long)bb * SDN;

    union RowU { ush8 v; unsigned u4[4]; unsigned short a[8]; };
    RowU r1[8], r2[8], c1[8], c2[8];
    #pragma unroll
    for (int r = 0; r < 8; ++r) {
        r1[r].v = *(const ush8*)(M1sT + ab + (long)(ib + r) * 2048 + jb);
        r2[r].v = *(const ush8*)(M2sT + ab + (long)(ib + r) * 2048 + jb);
    }
    __builtin_amdgcn_sched_barrier(0);
    #pragma unroll
    for (int p = 0; p < 4; ++p)
        #pragma unroll
        for (int k = 0; k < 4; ++k) {
            const unsigned a1 = r1[2*p].u4[k], b1 = r1[2*p+1].u4[k];
            c1[2*k].u4[p]   = (a1 & 0xffffu) | (b1 << 16);
            c1[2*k+1].u4[p] = (a1 >> 16) | (b1 & 0xffff0000u);
            const unsigned a2 = r2[2*p].u4[k], b2 = r2[2*p+1].u4[k];
            c2[2*k].u4[p]   = (a2 & 0xffffu) | (b2 << 16);
            c2[2*k+1].u4[p] = (a2 >> 16) | (b2 & 0xffff0000u);
        }
    #pragma unroll
    for (int jj = 0; jj < 8; ++jj) {
        const int j = jb + jj;
        const float rr = rs_raw[(long)bb * 2048 + j];
        const float cc = cs_raw[(long)bb * 2048 + j];
        float4 o0, o1;
        o0.x = fmaxf(0.5f * (bf2f(c1[jj].a[0]) * rr + bf2f(c2[jj].a[0]) * cc), 0.f);
        o0.y = fmaxf(0.5f * (bf2f(c1[jj].a[1]) * rr + bf2f(c2[jj].a[1]) * cc), 0.f);
        o0.z = fmaxf(0.5f * (bf2f(c1[jj].a[2]) * rr + bf2f(c2[jj].a[2]) * cc), 0.f);
        o0.w = fmaxf(0.5f * (bf2f(c1[jj].a[3]) * rr + bf2f(c2[jj].a[3]) * cc), 0.f);
        o1.x = fmaxf(0.5f * (bf2f(c1[jj].a[4]) * rr + bf2f(c2[jj].a[4]) * cc), 0.f);
        o1.y = fmaxf(0.5f * (bf2f(c1[jj].a[5]) * rr + bf2f(c2[jj].a[5]) * cc), 0.f);
        o1.z = fmaxf(0.5f * (bf2f(c1[jj].a[6]) * rr + bf2f(c2[jj].a[6]) * cc), 0.f);
        o1.w = fmaxf(0.5f * (bf2f(c1[jj].a[7]) * rr + bf2f(c2[jj].a[7]) * cc), 0.f);
        float* op = outp + ((long)bb * 2048 + j) * 768 + ib;
        *(float4*)op       = o0;
        *(float4*)(op + 4) = o1;
    }
}

// ---- gemmNE: NeT[d][n] = sum_k Hbf[n][k]*Wt[d][k]  (old-orientation, K=256)
__global__ __launch_bounds__(256) void gemmNE(
    const unsigned short* __restrict__ Hbf,    // tiled [b][16][2][128][128]
    const unsigned short* __restrict__ Wt,     // [256][256] row-major
    unsigned short* __restrict__ NeT)          // [b][256][2048]
{
    constexpr int TM = 128, K = 256, NT = 4;
    __shared__ __align__(16) unsigned short As[2][TM * 64];
    __shared__ __align__(16) unsigned short Bs[2][64 * 64];

    const int t  = threadIdx.x;
    const int bx = blockIdx.x;
    const int xcd = bx & 7;
    const int kk  = bx >> 3;
    const int itile = xcd + 8 * (kk >> 5);
    const int rem   = kk & 31;
    const int bb    = rem >> 2;
    const int jt    = rem & 3;
    const int i0b = itile * TM;
    const int j0  = jt * 64;

    const unsigned short* Btb = Wt + (long)j0 * K;
    const unsigned short* Ab  = Hbf + (long)bb * SDN;

    const int w = t >> 6, l = t & 63;
    const int wm = w >> 1, wn = w & 1;
    const int quad = l >> 4, c15 = l & 15;
    const int lr = l >> 3, ls = l & 7;

    floatx4 acc[4][2] = {};

    auto stage = [&](int buf, int k0) {
        const unsigned short* Au = Ab + (((long)itile * 2 + (k0 >> 7)) << 14);
        const int kin = k0 & 127;
        #pragma unroll
        for (int q = 0; q < 4; ++q) {
            const int rt = q * 32 + w * 8;
            gload_lds16(Au + (rt + lr) * 128 + kin + ((ls ^ lr) << 3),
                        &As[buf][rt * 64]);
        }
        #pragma unroll
        for (int q = 0; q < 2; ++q) {
            const int rt = q * 32 + w * 8;
            gload_lds16(Btb + (long)(rt + lr) * K + k0 + ((ls ^ lr) << 3),
                        &Bs[buf][rt * 64]);
        }
    };

    stage(0, 0);
    asm volatile("s_waitcnt vmcnt(0)" ::: "memory");
    __builtin_amdgcn_s_barrier();
    __builtin_amdgcn_sched_barrier(0);

    int cur = 0;
    for (int tt = 0; tt < NT; ++tt) {
        if (tt + 1 < NT) stage(cur ^ 1, (tt + 1) << 6);
        __builtin_amdgcn_sched_barrier(0);
        #pragma unroll
        for (int ks = 0; ks < 2; ++ks) {
            frag8 af[4], bfv[2];
            const int swr = c15 & 7;
            #pragma unroll
            for (int mt = 0; mt < 4; ++mt)
                af[mt] = *(const frag8*)&As[cur][(wm * 64 + mt * 16 + c15) * 64
                                               + (((ks * 4 + quad) ^ swr) << 3)];
            #pragma unroll
            for (int nt = 0; nt < 2; ++nt)
                bfv[nt] = *(const frag8*)&Bs[cur][(wn * 32 + nt * 16 + c15) * 64
                                                + (((ks * 4 + quad) ^ swr) << 3)];
            #pragma unroll
            for (int mt = 0; mt < 4; ++mt)
                #pragma unroll
                for (int nt = 0; nt < 2; ++nt)
                    acc[mt][nt] = __builtin_amdgcn_mfma_f32_16x16x32_bf16(
                        af[mt], bfv[nt], acc[mt][nt], 0, 0, 0);
        }
        if (tt + 1 < NT) {
            asm volatile("s_waitcnt vmcnt(0)" ::: "memory");
            __builtin_amdgcn_s_barrier();
            __builtin_amdgcn_sched_barrier(0);
        }
        cur ^= 1;
    }

    #pragma unroll
    for (int mt = 0; mt < 4; ++mt) {
        const int ib = i0b + wm * 64 + mt * 16 + quad * 4;
        #pragma unroll
        for (int nt = 0; nt < 2; ++nt) {
            const floatx4 v = acc[mt][nt];
            const int gj = j0 + wn * 32 + nt * 16 + c15;
            union { ushort4 v; ushort2 u2[2]; } p;
            p.u2[0] = pk2(v[0], v[1]); p.u2[1] = pk2(v[2], v[3]);
            *(ushort4*)(NeT + ((long)bb * 256 + gj) * 2048 + ib) = p.v;
        }
    }
}

// ---- cvt_stream: G fp32 -> Gbf (tiled) + FULL row sums + col partials ----
__global__ __launch_bounds__(256) void cvt_stream(
    const float* __restrict__ G,
    unsigned short* __restrict__ Gbf,          // tiled [16][16][128][128]
    float* __restrict__ pcs,                   // [b][128][2048] col partials
    float* __restrict__ inv_rs, float* __restrict__ rs_raw)
{
    __shared__ float sm[4][16];
    const int b  = blockIdx.y;
    const int s  = blockIdx.x;                 // strip 0..127
    const int i0 = s * 16;
    const int t  = threadIdx.x;
    const int c8 = t * 8;
    const int w  = t >> 6, l = t & 63;

    const float* gp = G + (long)b * GSTR + (long)i0 * NN + c8;
    unsigned short* gb = Gbf + (long)b * GSTR;
    const int tc = c8 >> 7, cin = c8 & 127;

    float csum[8] = {};
    float rp[16];

    #pragma unroll
    for (int r = 0; r < 16; ++r) {
        const float4 x0 = *(const float4*)(gp + (long)r * NN);
        const float4 x1 = *(const float4*)(gp + (long)r * NN + 4);
        union { ush8 v; ushort2 u2[4]; } pk;
        pk.u2[0] = pk2(x0.x, x0.y); pk.u2[1] = pk2(x0.z, x0.w);
        pk.u2[2] = pk2(x1.x, x1.y); pk.u2[3] = pk2(x1.z, x1.w);
        const int gi = i0 + r;
        *(ush8*)(gb + (((long)(gi >> 7) * 16 + tc) << 14) + ((gi & 127) << 7) + cin) = pk.v;
        rp[r] = x0.x + x0.y + x0.z + x0.w + x1.x + x1.y + x1.z + x1.w;
        csum[0] += x0.x; csum[1] += x0.y; csum[2] += x0.z; csum[3] += x0.w;
        csum[4] += x1.x; csum[5] += x1.y; csum[6] += x1.z; csum[7] += x1.w;
    }

    float* pp = pcs + ((long)b * 128 + s) * NN + c8;
    *(float4*)pp       = make_float4(csum[0], csum[1], csum[2], csum[3]);
    *(float4*)(pp + 4) = make_float4(csum[4], csum[5], csum[6], csum[7]);

    #pragma unroll
    for (int r = 0; r < 16; ++r) {
        rp[r] += __shfl_xor(rp[r], 1);
        rp[r] += __shfl_xor(rp[r], 2);
        rp[r] += __shfl_xor(rp[r], 4);
        rp[r] += __shfl_xor(rp[r], 8);
        rp[r] += __shfl_xor(rp[r], 16);
        rp[r] += __shfl_xor(rp[r], 32);
    }
    if (l == 0) {
        #pragma unroll
        for (int r = 0; r < 16; ++r) sm[w][r] = rp[r];
    }
    __syncthreads();
    if (t < 16) {
        const float s_ = sm[0][t] + sm[1][t] + sm[2][t] + sm[3][t];
        rs_raw[(long)b * NN + i0 + t] = s_;
        inv_rs[(long)b * NN + i0 + t] = 1.0f / s_;
    }
}

// ---- cvt_t: tiled->tiled bf16 transpose. Block = one 128x128 tile.
__global__ __launch_bounds__(256) void cvt_t(
    const unsigned short* __restrict__ Gbf, unsigned short* __restrict__ GbfT)
{
    const int b  = blockIdx.z;
    const int tr = blockIdx.y, tc = blockIdx.x;
    const long src = (long)b * GSTR + (((long)tr * 16 + tc) << 14);
    const long dst = (long)b * GSTR + (((long)tc * 16 + tr) << 14);
    const int t = threadIdx.x;
    const int w = t >> 6, l = t & 63;
    const int wm = w >> 1, wn = w & 1;
    const int rg = l >> 3, c = l & 7;
    const int il = wm * 64 + rg * 8;
    const int jl = wn * 64 + c * 8;

    union RowU { ush8 v; unsigned u4[4]; };
    RowU rows[8], cols[8];
    #pragma unroll
    for (int r = 0; r < 8; ++r)
        rows[r].v = *(const ush8*)(Gbf + src + (long)(il + r) * 128 + jl);
    __builtin_amdgcn_sched_barrier(0);

    #pragma unroll
    for (int p = 0; p < 4; ++p)
        #pragma unroll
        for (int k = 0; k < 4; ++k) {
            const unsigned a = rows[2 * p].u4[k], bq = rows[2 * p + 1].u4[k];
            cols[2 * k].u4[p]     = (a & 0xffffu) | (bq << 16);
            cols[2 * k + 1].u4[p] = (a >> 16) | (bq & 0xffff0000u);
        }
    #pragma unroll
    for (int j = 0; j < 8; ++j)
        *(ush8*)(GbfT + dst + (long)(jl + j) * 128 + il) = cols[j].v;
}

// ---- cvt_h: H fp32 [b][2048][256] -> Hbf tiled [b][16][2][128][128] bf16 ----
__global__ __launch_bounds__(256) void cvt_h(
    const float* __restrict__ H, unsigned short* __restrict__ Hbf)
{
    const int b = blockIdx.y, it = blockIdx.x;
    const int t = threadIdx.x;
    const int rsub = t >> 5, c = (t & 31) * 8;
    const float* hp = H + ((long)b * 2048 + (long)it * 128) * 256;
    unsigned short* ob = Hbf + (long)b * SDN + (((long)it * 2 + (c >> 7)) << 14);
    const int cin = c & 127;
    #pragma unroll
    for (int rr = 0; rr < 16; ++rr) {
        const int r = rr * 8 + rsub;
        const float4 x0 = *(const float4*)(hp + (long)r * 256 + c);
        const float4 x1 = *(const float4*)(hp + (long)r * 256 + c + 4);
        union { ush8 v; ushort2 u2[4]; } pk;
        pk.u2[0] = pk2(x0.x, x0.y); pk.u2[1] = pk2(x0.z, x0.w);
        pk.u2[2] = pk2(x1.x, x1.y); pk.u2[3] = pk2(x1.z, x1.w);
        *(ush8*)(ob + r * 128 + cin) = pk.v;
    }
}

// reduce col partials + W transpose: y=0 -> inv_cs+cs_raw ; y=1 -> Wt
__global__ __launch_bounds__(256) void finalize(
    const float* __restrict__ pcs,
    float* __restrict__ inv_cs, float* __restrict__ cs_raw,
    const float* __restrict__ W, unsigned short* __restrict__ Wt)
{
    const int idx = blockIdx.x * 256 + threadIdx.x;   // 0..16383
    if (blockIdx.y == 0) {
        const int b = idx >> 11, i = idx & 2047;
        float s = 0.f;
        for (int ic = 0; ic < 128; ++ic) s += pcs[((long)b * 128 + ic) * NN + i];
        inv_cs[idx] = 1.0f / s;
        cs_raw[idx] = s;
    } else {
        #pragma unroll
        for (int e = 0; e < 4; ++e) {
            const int flat = idx * 4 + e;              // 0..65535
            const int j = flat >> 8, k = flat & 255;
            Wt[flat] = f2bf(W[(long)k * 256 + j]);
        }
    }
}

extern "C" void kernel_launch(void* const* d_in, const int* in_sizes, int n_in,
                              void* d_out, int out_size, void* d_ws, size_t ws_size,
                              hipStream_t stream)
{
    constexpr int B = 8;
    const float* H = (const float*)d_in[0];
    const float* G = (const float*)d_in[1];
    const float* W = (const float*)d_in[2];
    float* out = (float*)d_out;

    unsigned short* ws16 = (unsigned short*)d_ws;
    unsigned short* Gbf  = ws16;                          // 33,554,432 shorts (tiled)
    unsigned short* GbfT = Gbf  + (long)B * GSTR;         // 33,554,432 (tiled)
    unsigned short* Wt   = GbfT + (long)B * GSTR;         // 65,536
    unsigned short* NeT  = Wt   + 65536;                  // 4,194,304 [b][256][2048]
    unsigned short* M1sT = NeT  + 4194304;                // 4,194,304
    unsigned short* M2sT = M1sT + 4194304;                // 4,194,304
    unsigned short* Hbf  = M2sT + 4194304;                // 4,194,304 (tiled)
    float* inv_rs = (float*)(Hbf + 4194304);              // 16384
    float* rs_raw = inv_rs + 16384;
    float* inv_cs = rs_raw + 16384;
    float* cs_raw = inv_cs + 16384;
    float* pcs    = cs_raw + 16384;                       // 8*128*2048 = 2M floats
    // total ~177 MB (ws = 512 MiB)

    cvt_stream<<<dim3(128, 8), 256, 0, stream>>>(G, Gbf, pcs, inv_rs, rs_raw);
    cvt_t<<<dim3(16, 16, 8), 256, 0, stream>>>(Gbf, GbfT);
    cvt_h<<<dim3(16, 8), 256, 0, stream>>>(H, Hbf);
    finalize<<<dim3(64, 2), 256, 0, stream>>>(pcs, inv_cs, cs_raw, W, Wt);

    // NeT = (H@W)^T
    gemmNE<<<512, 256, 0, stream>>>(Hbf, Wt, NeT);
    // GA: M1sT (h=0, B=Gbf) + M2sT (h=1, B=GbfT), A=NeT L2-resident per XCD
    gemmF<0><<<512, 256, 0, stream>>>(NeT, nullptr, Gbf, GbfT,
                                      M1sT, M2sT, nullptr, inv_rs, inv_cs);
    // GB: out1 (h=0, A=M1sT, B=GbfT) + out2 (h=1, A=M2sT, B=Gbf)
    gemmF<1><<<512, 256, 0, stream>>>(M1sT, M2sT, Gbf, GbfT,
                                      nullptr, nullptr, out, nullptr, nullptr);
    // out0 from M1sT/M2sT reconstruct
    out0k<<<dim3(32, 8), 256, 0, stream>>>(M1sT, M2sT, rs_raw, cs_raw, out);
}